// Round 1
// baseline (119.903 us; speedup 1.0000x reference)
//
#include <hip/hip_runtime.h>
#include <hip/hip_cooperative_groups.h>

namespace cg = cooperative_groups;

// Reference telescopes: kl_loss = mean(log_q_z_given_x) - mean(log_prior).
// log_qz / log_qz_product (the O(B^2*D) pairwise work) cancel exactly and
// never appear in the output tuple. dataset_size is unused.
//
// Per-element kl term (i,d):
//   lq - lp = -0.5*((z-mu)^2*exp(-lv) + lv + L2PI) + 0.5*(z^2*exp(-1) + 1 + L2PI)
//           = -0.5*((z-mu)^2*exp(-lv) + lv) + 0.5*(z^2*0.36787944 + 1)
//
// This round: single cooperative kernel (grid.sync + block-0 finalize) to
// drop the second dispatch, and compile-time stride so the 4-iteration
// recon grid-stride loop fully unrolls (8 global_load_dwordx4 in flight
// before the first waitcnt instead of one latency per iteration).
// Accumulation order is bit-identical to the previous 2-kernel version.

#define B_SZ      2048
#define T_SZ      512
#define D_SZ      32
#define N_RECON4  (B_SZ * T_SZ / 4)   // 262144 float4
#define N_KL4     (B_SZ * D_SZ / 4)   // 16384 float4
#define NBLOCKS   256
#define NTHREADS  256
#define STRIDE    (NBLOCKS * NTHREADS) // 65536, compile-time

__device__ __forceinline__ float kl_elem(float z, float m, float lv) {
    float t = z - m;
    return -0.5f * (t * t * __expf(-lv) + lv)
         + 0.5f * (z * z * 0.36787944117144233f + 1.0f);
}

__global__ __launch_bounds__(NTHREADS) void tcvae_fused(
    const float* __restrict__ recon, const float* __restrict__ x,
    const float* __restrict__ mu, const float* __restrict__ lv,
    const float* __restrict__ z, float* __restrict__ partials,
    float* __restrict__ out)
{
    const int tid = blockIdx.x * NTHREADS + threadIdx.x;

    float racc = 0.0f, kacc = 0.0f;

    // ---- recon MAE partial: 4 statically-unrolled iterations ----
    const float4* x4 = (const float4*)x;
    const float4* r4 = (const float4*)recon;
    #pragma unroll
    for (int k = 0; k < N_RECON4 / STRIDE; ++k) {   // trip count 4, known
        const int i = tid + k * STRIDE;
        float4 a = x4[i], b = r4[i];
        racc += fabsf(a.x - b.x) + fabsf(a.y - b.y)
              + fabsf(a.z - b.z) + fabsf(a.w - b.w);
    }

    // ---- kl partial: N_KL4 (16384) < STRIDE, single predicated iter ----
    if (tid < N_KL4) {
        float4 zz = ((const float4*)z)[tid];
        float4 mm = ((const float4*)mu)[tid];
        float4 ll = ((const float4*)lv)[tid];
        kacc = kl_elem(zz.x, mm.x, ll.x) + kl_elem(zz.y, mm.y, ll.y)
             + kl_elem(zz.z, mm.z, ll.z) + kl_elem(zz.w, mm.w, ll.w);
    }

    // ---- wave (64-lane) reduction ----
    #pragma unroll
    for (int off = 32; off > 0; off >>= 1) {
        racc += __shfl_down(racc, off, 64);
        kacc += __shfl_down(kacc, off, 64);
    }

    __shared__ float sr[4], sk[4];
    const int lane = threadIdx.x & 63;
    const int wid  = threadIdx.x >> 6;
    if (lane == 0) { sr[wid] = racc; sk[wid] = kacc; }
    __syncthreads();
    if (threadIdx.x == 0) {
        partials[blockIdx.x]           = sr[0] + sr[1] + sr[2] + sr[3];
        partials[NBLOCKS + blockIdx.x] = sk[0] + sk[1] + sk[2] + sk[3];
    }
    __threadfence();          // device-scope: make partials visible cross-XCD

    cg::this_grid().sync();

    // ---- finalize in block 0 (same order as old tcvae_final) ----
    if (blockIdx.x == 0) {
        float r2 = 0.0f, k2 = 0.0f;
        for (int i = threadIdx.x; i < NBLOCKS; i += NTHREADS) {
            r2 += partials[i];
            k2 += partials[NBLOCKS + i];
        }
        #pragma unroll
        for (int off = 32; off > 0; off >>= 1) {
            r2 += __shfl_down(r2, off, 64);
            k2 += __shfl_down(k2, off, 64);
        }
        if (lane == 0) { sr[wid] = r2; sk[wid] = k2; }
        __syncthreads();
        if (threadIdx.x == 0) {
            float r = (sr[0] + sr[1] + sr[2] + sr[3]) * (1.0f / (float)(B_SZ * T_SZ));
            float k = (sk[0] + sk[1] + sk[2] + sk[3]) * (1.0f / (float)B_SZ);
            out[0] = r + k;   // total_loss
            out[1] = r;       // recon_loss
            out[2] = k;       // kl_loss
        }
    }
}

extern "C" void kernel_launch(void* const* d_in, const int* in_sizes, int n_in,
                              void* d_out, int out_size, void* d_ws, size_t ws_size,
                              hipStream_t stream) {
    const float* recon = (const float*)d_in[0];
    const float* x     = (const float*)d_in[1];
    const float* mu    = (const float*)d_in[2];
    const float* lv    = (const float*)d_in[3];
    const float* z     = (const float*)d_in[4];
    // d_in[5] (dataset_size) is algebraically unused in the outputs.

    float* partials = (float*)d_ws;        // 2 * NBLOCKS floats
    float* out      = (float*)d_out;       // 3 floats

    void* args[] = { (void*)&recon, (void*)&x, (void*)&mu, (void*)&lv,
                     (void*)&z, (void*)&partials, (void*)&out };
    hipLaunchCooperativeKernel((const void*)tcvae_fused,
                               dim3(NBLOCKS), dim3(NTHREADS),
                               args, 0, stream);
}

// Round 2
// 72.856 us; speedup vs baseline: 1.6458x; 1.6458x over previous
//
#include <hip/hip_runtime.h>

// Reference telescopes: kl_loss = mean(log_q_z_given_x) - mean(log_prior).
// log_qz / log_qz_product (the O(B^2*D) pairwise work) cancel exactly and
// never appear in the output tuple. dataset_size is unused.
//
// Per-element kl term (i,d):
//   lq - lp = -0.5*((z-mu)^2*exp(-lv) + lv + L2PI) + 0.5*(z^2*exp(-1) + 1 + L2PI)
//           = -0.5*((z-mu)^2*exp(-lv) + lv) + 0.5*(z^2*0.36787944 + 1)
//
// Round 1 post-mortem: hipLaunchCooperativeKernel cost ~+50us of launch
// machinery inside the captured graph. This round: single ORDINARY launch,
// last-block-ticket finalize. Partials + ticket live in __device__ globals
// (not the poisoned workspace); publication uses device-scope atomics so
// cross-XCD L2 non-coherence is irrelevant. Ticket test is (t % NBLOCKS)
// == NBLOCKS-1 so the monotone counter stays correct across graph replays
// with no reset race. Final-reduce order is bit-identical to the old
// tcvae_final kernel (thread i reads partial i, same shuffle tree).

#define B_SZ      2048
#define T_SZ      512
#define D_SZ      32
#define N_RECON4  (B_SZ * T_SZ / 4)   // 262144 float4
#define N_KL4     (B_SZ * D_SZ / 4)   // 16384 float4
#define NBLOCKS   256
#define NTHREADS  256
#define STRIDE    (NBLOCKS * NTHREADS) // 65536, compile-time

__device__ float        g_part_r[NBLOCKS];
__device__ float        g_part_k[NBLOCKS];
__device__ unsigned int g_ticket = 0;   // monotone across graph replays

__device__ __forceinline__ float kl_elem(float z, float m, float lv) {
    float t = z - m;
    return -0.5f * (t * t * __expf(-lv) + lv)
         + 0.5f * (z * z * 0.36787944117144233f + 1.0f);
}

__global__ __launch_bounds__(NTHREADS) void tcvae_onepass(
    const float* __restrict__ recon, const float* __restrict__ x,
    const float* __restrict__ mu, const float* __restrict__ lv,
    const float* __restrict__ z, float* __restrict__ out)
{
    const int tid = blockIdx.x * NTHREADS + threadIdx.x;

    float racc = 0.0f, kacc = 0.0f;

    // ---- recon MAE partial: 4 statically-unrolled iterations ----
    const float4* x4 = (const float4*)x;
    const float4* r4 = (const float4*)recon;
    #pragma unroll
    for (int k = 0; k < N_RECON4 / STRIDE; ++k) {   // trip count 4, known
        const int i = tid + k * STRIDE;
        float4 a = x4[i], b = r4[i];
        racc += fabsf(a.x - b.x) + fabsf(a.y - b.y)
              + fabsf(a.z - b.z) + fabsf(a.w - b.w);
    }

    // ---- kl partial: N_KL4 (16384) < STRIDE, single predicated iter ----
    if (tid < N_KL4) {
        float4 zz = ((const float4*)z)[tid];
        float4 mm = ((const float4*)mu)[tid];
        float4 ll = ((const float4*)lv)[tid];
        kacc = kl_elem(zz.x, mm.x, ll.x) + kl_elem(zz.y, mm.y, ll.y)
             + kl_elem(zz.z, mm.z, ll.z) + kl_elem(zz.w, mm.w, ll.w);
    }

    // ---- wave (64-lane) reduction ----
    #pragma unroll
    for (int off = 32; off > 0; off >>= 1) {
        racc += __shfl_down(racc, off, 64);
        kacc += __shfl_down(kacc, off, 64);
    }

    __shared__ float sr[4], sk[4];
    __shared__ int s_last;
    const int lane = threadIdx.x & 63;
    const int wid  = threadIdx.x >> 6;
    if (lane == 0) { sr[wid] = racc; sk[wid] = kacc; }
    __syncthreads();

    // ---- publish block partial, take ticket (thread 0) ----
    if (threadIdx.x == 0) {
        float br = sr[0] + sr[1] + sr[2] + sr[3];
        float bk = sk[0] + sk[1] + sk[2] + sk[3];
        atomicExch(&g_part_r[blockIdx.x], br);   // device-scope, coherent point
        atomicExch(&g_part_k[blockIdx.x], bk);
        __threadfence();                          // release before ticket
        unsigned int t = atomicAdd(&g_ticket, 1u);
        s_last = ((t % NBLOCKS) == NBLOCKS - 1) ? 1 : 0;
    }
    __syncthreads();

    // ---- last block finalizes (order identical to old tcvae_final) ----
    if (s_last) {
        __threadfence();                          // acquire
        const int i = threadIdx.x;                // NTHREADS == NBLOCKS
        float r2 = atomicAdd(&g_part_r[i], 0.0f); // coherent read (returns old)
        float k2 = atomicAdd(&g_part_k[i], 0.0f);
        #pragma unroll
        for (int off = 32; off > 0; off >>= 1) {
            r2 += __shfl_down(r2, off, 64);
            k2 += __shfl_down(k2, off, 64);
        }
        if (lane == 0) { sr[wid] = r2; sk[wid] = k2; }
        __syncthreads();
        if (threadIdx.x == 0) {
            float r = (sr[0] + sr[1] + sr[2] + sr[3]) * (1.0f / (float)(B_SZ * T_SZ));
            float k = (sk[0] + sk[1] + sk[2] + sk[3]) * (1.0f / (float)B_SZ);
            out[0] = r + k;   // total_loss
            out[1] = r;       // recon_loss
            out[2] = k;       // kl_loss
        }
    }
}

extern "C" void kernel_launch(void* const* d_in, const int* in_sizes, int n_in,
                              void* d_out, int out_size, void* d_ws, size_t ws_size,
                              hipStream_t stream) {
    const float* recon = (const float*)d_in[0];
    const float* x     = (const float*)d_in[1];
    const float* mu    = (const float*)d_in[2];
    const float* lv    = (const float*)d_in[3];
    const float* z     = (const float*)d_in[4];
    // d_in[5] (dataset_size) is algebraically unused in the outputs.

    float* out = (float*)d_out;   // 3 floats
    (void)d_ws; (void)ws_size;    // partials live in __device__ globals

    tcvae_onepass<<<NBLOCKS, NTHREADS, 0, stream>>>(recon, x, mu, lv, z, out);
}

// Round 3
// 69.103 us; speedup vs baseline: 1.7351x; 1.0543x over previous
//
#include <hip/hip_runtime.h>

// Reference telescopes: kl_loss = mean(log_q_z_given_x) - mean(log_prior).
// log_qz / log_qz_product (the O(B^2*D) pairwise work) cancel exactly and
// never appear in the output tuple. dataset_size is unused.
//
// Per-element kl term (i,d):
//   lq - lp = -0.5*((z-mu)^2*exp(-lv) + lv + L2PI) + 0.5*(z^2*exp(-1) + 1 + L2PI)
//           = -0.5*((z-mu)^2*exp(-lv) + lv) + 0.5*(z^2*0.36787944 + 1)
//
// Session findings (R0-R2):
//   - cooperative launch inside the captured graph: +50us (R1) — never.
//   - 1 regular kernel (ticket finalize) vs 2 regular kernels: neutral
//     within noise (R2) — node count is not the lever.
//   - Timed floor is harness-fixed: unconditional 256MiB ws poison fill
//     (40-43us @ ~83% HBM) + reset nodes; our 8.75MB of reads is ~1.4us
//     of traffic. Reverting to the best-measured 2-kernel structure.
//   - Kept from R1: compile-time STRIDE -> recon loop fully unrolls
//     (8 global_load_dwordx4 issued before first s_waitcnt), KL loop is
//     one predicated iteration. Accumulation order identical to baseline.

#define B_SZ      2048
#define T_SZ      512
#define D_SZ      32
#define N_RECON4  (B_SZ * T_SZ / 4)   // 262144 float4
#define N_KL4     (B_SZ * D_SZ / 4)   // 16384 float4
#define NBLOCKS   256
#define NTHREADS  256
#define STRIDE    (NBLOCKS * NTHREADS) // 65536, compile-time

__device__ __forceinline__ float kl_elem(float z, float m, float lv) {
    float t = z - m;
    return -0.5f * (t * t * __expf(-lv) + lv)
         + 0.5f * (z * z * 0.36787944117144233f + 1.0f);
}

__global__ __launch_bounds__(NTHREADS) void tcvae_partial(
    const float* __restrict__ recon, const float* __restrict__ x,
    const float* __restrict__ mu, const float* __restrict__ lv,
    const float* __restrict__ z, float* __restrict__ partials)
{
    const int tid = blockIdx.x * NTHREADS + threadIdx.x;

    float racc = 0.0f, kacc = 0.0f;

    // ---- recon MAE partial: 4 statically-unrolled iterations ----
    const float4* x4 = (const float4*)x;
    const float4* r4 = (const float4*)recon;
    #pragma unroll
    for (int k = 0; k < N_RECON4 / STRIDE; ++k) {   // trip count 4, known
        const int i = tid + k * STRIDE;
        float4 a = x4[i], b = r4[i];
        racc += fabsf(a.x - b.x) + fabsf(a.y - b.y)
              + fabsf(a.z - b.z) + fabsf(a.w - b.w);
    }

    // ---- kl partial: N_KL4 (16384) < STRIDE, single predicated iter ----
    if (tid < N_KL4) {
        float4 zz = ((const float4*)z)[tid];
        float4 mm = ((const float4*)mu)[tid];
        float4 ll = ((const float4*)lv)[tid];
        kacc = kl_elem(zz.x, mm.x, ll.x) + kl_elem(zz.y, mm.y, ll.y)
             + kl_elem(zz.z, mm.z, ll.z) + kl_elem(zz.w, mm.w, ll.w);
    }

    // ---- wave (64-lane) reduction ----
    #pragma unroll
    for (int off = 32; off > 0; off >>= 1) {
        racc += __shfl_down(racc, off, 64);
        kacc += __shfl_down(kacc, off, 64);
    }

    __shared__ float sr[4], sk[4];
    const int lane = threadIdx.x & 63;
    const int wid  = threadIdx.x >> 6;
    if (lane == 0) { sr[wid] = racc; sk[wid] = kacc; }
    __syncthreads();
    if (threadIdx.x == 0) {
        partials[blockIdx.x]           = sr[0] + sr[1] + sr[2] + sr[3];
        partials[NBLOCKS + blockIdx.x] = sk[0] + sk[1] + sk[2] + sk[3];
    }
}

__global__ __launch_bounds__(NTHREADS) void tcvae_final(
    const float* __restrict__ partials, float* __restrict__ out)
{
    float racc = 0.0f, kacc = 0.0f;
    const int i = threadIdx.x;                 // NTHREADS == NBLOCKS
    racc = partials[i];
    kacc = partials[NBLOCKS + i];

    #pragma unroll
    for (int off = 32; off > 0; off >>= 1) {
        racc += __shfl_down(racc, off, 64);
        kacc += __shfl_down(kacc, off, 64);
    }

    __shared__ float sr[4], sk[4];
    const int lane = threadIdx.x & 63;
    const int wid  = threadIdx.x >> 6;
    if (lane == 0) { sr[wid] = racc; sk[wid] = kacc; }
    __syncthreads();
    if (threadIdx.x == 0) {
        float r = (sr[0] + sr[1] + sr[2] + sr[3]) * (1.0f / (float)(B_SZ * T_SZ));
        float k = (sk[0] + sk[1] + sk[2] + sk[3]) * (1.0f / (float)B_SZ);
        out[0] = r + k;   // total_loss
        out[1] = r;       // recon_loss
        out[2] = k;       // kl_loss
    }
}

extern "C" void kernel_launch(void* const* d_in, const int* in_sizes, int n_in,
                              void* d_out, int out_size, void* d_ws, size_t ws_size,
                              hipStream_t stream) {
    const float* recon = (const float*)d_in[0];
    const float* x     = (const float*)d_in[1];
    const float* mu    = (const float*)d_in[2];
    const float* lv    = (const float*)d_in[3];
    const float* z     = (const float*)d_in[4];
    // d_in[5] (dataset_size) is algebraically unused in the outputs.

    float* partials = (float*)d_ws;        // 2 * NBLOCKS floats
    float* out      = (float*)d_out;       // 3 floats

    tcvae_partial<<<NBLOCKS, NTHREADS, 0, stream>>>(recon, x, mu, lv, z, partials);
    tcvae_final<<<1, NTHREADS, 0, stream>>>(partials, out);
}